// Round 1
// baseline (194.254 us; speedup 1.0000x reference)
//
#include <hip/hip_runtime.h>

#define BLOCK 256
#define GRID  2048

// Each 32-lane half-wave processes one row of 128 floats (lane -> one float4).
// Three simultaneous reductions (pp, tt, pt) via shfl_xor butterfly.
__global__ __launch_bounds__(BLOCK) void triplet_partial_kernel(
    const float* __restrict__ targets, const float* __restrict__ preds,
    float* __restrict__ partial, int nrows)
{
    const int tid = threadIdx.x;
    const int lw  = tid & 31;                                   // lane within half-wave
    const int hw  = (blockIdx.x * BLOCK + tid) >> 5;            // global half-wave id
    const int nhw = (gridDim.x * BLOCK) >> 5;                   // total half-waves

    float acc = 0.0f;
    for (int r = hw; r < nrows; r += nhw) {
        const float4* pr = reinterpret_cast<const float4*>(preds   + (size_t)r * 128);
        const float4* tr = reinterpret_cast<const float4*>(targets + (size_t)r * 128);
        float4 p = pr[lw];
        float4 t = tr[lw];
        float pp = p.x*p.x + p.y*p.y + p.z*p.z + p.w*p.w;
        float tt = t.x*t.x + t.y*t.y + t.z*t.z + t.w*t.w;
        float pt = p.x*t.x + p.y*t.y + p.z*t.z + p.w*t.w;
        #pragma unroll
        for (int m = 1; m <= 16; m <<= 1) {
            pp += __shfl_xor(pp, m);
            tt += __shfl_xor(tt, m);
            pt += __shfl_xor(pt, m);
        }
        // loss per row (all 32 lanes hold identical sums)
        float pt2  = pt * pt;
        float nn   = fmaxf(pp - 2.0f * pt2 + pt2 * tt, 0.0f);
        float norm = fmaxf(sqrtf(nn), 1e-12f);
        float spn  = (pp - pt2) / norm;
        acc += fmaxf(0.5f + spn - pt, 0.0f);
    }

    // block reduction: 8 half-waves per block, lane 0 of each contributes
    __shared__ float sacc[BLOCK / 32];
    if (lw == 0) sacc[tid >> 5] = acc;
    __syncthreads();
    if (tid == 0) {
        float s = 0.0f;
        #pragma unroll
        for (int i = 0; i < BLOCK / 32; ++i) s += sacc[i];
        partial[blockIdx.x] = s;
    }
}

// Deterministic single-block final reduction -> mean.
__global__ __launch_bounds__(BLOCK) void triplet_final_kernel(
    const float* __restrict__ partial, float* __restrict__ out,
    int n, float inv_nrows)
{
    float s = 0.0f;
    for (int i = threadIdx.x; i < n; i += BLOCK) s += partial[i];
    #pragma unroll
    for (int m = 1; m <= 32; m <<= 1) s += __shfl_xor(s, m);   // full wave64 reduce
    __shared__ float sw[BLOCK / 64];
    if ((threadIdx.x & 63) == 0) sw[threadIdx.x >> 6] = s;
    __syncthreads();
    if (threadIdx.x == 0) {
        float tot = 0.0f;
        #pragma unroll
        for (int i = 0; i < BLOCK / 64; ++i) tot += sw[i];
        out[0] = tot * inv_nrows;
    }
}

extern "C" void kernel_launch(void* const* d_in, const int* in_sizes, int n_in,
                              void* d_out, int out_size, void* d_ws, size_t ws_size,
                              hipStream_t stream) {
    const float* targets = (const float*)d_in[0];
    const float* preds   = (const float*)d_in[1];
    float* partial = (float*)d_ws;          // GRID floats of scratch
    float* out     = (float*)d_out;

    const int nrows = in_sizes[0] / 128;    // 1048576

    triplet_partial_kernel<<<GRID, BLOCK, 0, stream>>>(targets, preds, partial, nrows);
    triplet_final_kernel<<<1, BLOCK, 0, stream>>>(partial, out, GRID, 1.0f / (float)nrows);
}

// Round 2
// 172.729 us; speedup vs baseline: 1.1246x; 1.1246x over previous
//
#include <hip/hip_runtime.h>

#define BLOCK 256
#define GRID  2048

typedef float f32x4 __attribute__((ext_vector_type(4)));

__device__ inline void dots(f32x4 p, f32x4 t, float& pp, float& tt, float& pt) {
    pp = p.x*p.x + p.y*p.y + p.z*p.z + p.w*p.w;
    tt = t.x*t.x + t.y*t.y + t.z*t.z + t.w*t.w;
    pt = p.x*t.x + p.y*t.y + p.z*t.z + p.w*t.w;
}

__device__ inline float row_loss(float pp, float tt, float pt) {
    float pt2  = pt * pt;
    float nn   = fmaxf(pp - 2.0f * pt2 + pt2 * tt, 0.0f);
    float norm = fmaxf(sqrtf(nn), 1e-12f);
    float spn  = (pp - pt2) / norm;
    return fmaxf(0.5f + spn - pt, 0.0f);
}

// Each 32-lane half-wave processes rows; lane -> one float4 (16B) per array.
// Unroll x2 with all 4 loads issued up front (64B/thread in flight).
__global__ __launch_bounds__(BLOCK) void triplet_partial_kernel(
    const float* __restrict__ targets, const float* __restrict__ preds,
    float* __restrict__ partial, int nrows)
{
    const int tid = threadIdx.x;
    const int lw  = tid & 31;
    const int hw  = (blockIdx.x * BLOCK + tid) >> 5;
    const int nhw = (gridDim.x * BLOCK) >> 5;

    float acc = 0.0f;
    int r = hw;
    for (; r + nhw < nrows; r += 2 * nhw) {
        const f32x4* p0p = reinterpret_cast<const f32x4*>(preds   + (size_t)r * 128) + lw;
        const f32x4* t0p = reinterpret_cast<const f32x4*>(targets + (size_t)r * 128) + lw;
        const f32x4* p1p = reinterpret_cast<const f32x4*>(preds   + (size_t)(r + nhw) * 128) + lw;
        const f32x4* t1p = reinterpret_cast<const f32x4*>(targets + (size_t)(r + nhw) * 128) + lw;
        f32x4 p0 = __builtin_nontemporal_load(p0p);
        f32x4 t0 = __builtin_nontemporal_load(t0p);
        f32x4 p1 = __builtin_nontemporal_load(p1p);
        f32x4 t1 = __builtin_nontemporal_load(t1p);

        float pp0, tt0, pt0, pp1, tt1, pt1;
        dots(p0, t0, pp0, tt0, pt0);
        dots(p1, t1, pp1, tt1, pt1);

        #pragma unroll
        for (int m = 1; m <= 16; m <<= 1) {
            pp0 += __shfl_xor(pp0, m);
            pp1 += __shfl_xor(pp1, m);
            tt0 += __shfl_xor(tt0, m);
            tt1 += __shfl_xor(tt1, m);
            pt0 += __shfl_xor(pt0, m);
            pt1 += __shfl_xor(pt1, m);
        }
        acc += row_loss(pp0, tt0, pt0);
        acc += row_loss(pp1, tt1, pt1);
    }
    for (; r < nrows; r += nhw) {
        const f32x4* pr = reinterpret_cast<const f32x4*>(preds   + (size_t)r * 128) + lw;
        const f32x4* tr = reinterpret_cast<const f32x4*>(targets + (size_t)r * 128) + lw;
        f32x4 p = __builtin_nontemporal_load(pr);
        f32x4 t = __builtin_nontemporal_load(tr);
        float pp, tt, pt;
        dots(p, t, pp, tt, pt);
        #pragma unroll
        for (int m = 1; m <= 16; m <<= 1) {
            pp += __shfl_xor(pp, m);
            tt += __shfl_xor(tt, m);
            pt += __shfl_xor(pt, m);
        }
        acc += row_loss(pp, tt, pt);
    }

    __shared__ float sacc[BLOCK / 32];
    if (lw == 0) sacc[tid >> 5] = acc;
    __syncthreads();
    if (tid == 0) {
        float s = 0.0f;
        #pragma unroll
        for (int i = 0; i < BLOCK / 32; ++i) s += sacc[i];
        partial[blockIdx.x] = s;
    }
}

// Deterministic single-block final reduction -> mean.
__global__ __launch_bounds__(BLOCK) void triplet_final_kernel(
    const float* __restrict__ partial, float* __restrict__ out,
    int n, float inv_nrows)
{
    float s = 0.0f;
    for (int i = threadIdx.x; i < n; i += BLOCK) s += partial[i];
    #pragma unroll
    for (int m = 1; m <= 32; m <<= 1) s += __shfl_xor(s, m);
    __shared__ float sw[BLOCK / 64];
    if ((threadIdx.x & 63) == 0) sw[threadIdx.x >> 6] = s;
    __syncthreads();
    if (threadIdx.x == 0) {
        float tot = 0.0f;
        #pragma unroll
        for (int i = 0; i < BLOCK / 64; ++i) tot += sw[i];
        out[0] = tot * inv_nrows;
    }
}

extern "C" void kernel_launch(void* const* d_in, const int* in_sizes, int n_in,
                              void* d_out, int out_size, void* d_ws, size_t ws_size,
                              hipStream_t stream) {
    const float* targets = (const float*)d_in[0];
    const float* preds   = (const float*)d_in[1];
    float* partial = (float*)d_ws;
    float* out     = (float*)d_out;

    const int nrows = in_sizes[0] / 128;

    triplet_partial_kernel<<<GRID, BLOCK, 0, stream>>>(targets, preds, partial, nrows);
    triplet_final_kernel<<<1, BLOCK, 0, stream>>>(partial, out, GRID, 1.0f / (float)nrows);
}